// Round 6
// baseline (506.399 us; speedup 1.0000x reference)
//
#include <hip/hip_runtime.h>
#include <math.h>

static constexpr int BT  = 512;    // batch
static constexpr int TT  = 2048;   // time steps
static constexpr int NCH = BT * 8; // 4096 chains

// f64-derived constants, cast to f32 exactly as the reference does
static constexpr float C00 = (float)(1000.0 / (1.0 - 0.09));            // D[0][0]
static constexpr float C01 = (float)((1000.0 / (1.0 - 0.09)) * 0.3);    // D[0][1]
static constexpr float C22 = (float)((1000.0 / (1.0 - 0.09)) * 0.35);   // D[2][2]
static constexpr float INV3GH = (float)(1.0 / (3.0 * (1000.0 / 2.6) + 100.0));

__device__ __forceinline__ float softplus_f(float v) {
    return fmaxf(v, 0.0f) + log1pf(expf(-fabsf(v)));
}

// ---------------------------------------------------------------------------
// K1: projections + damage candidate. One thread per (b,t).
// arr[g][t][lane] float4 = (d_new, De_xx, De_yy, De_xy);
// g = b>>3, lane = (b&7)*8 + p.  (unchanged from round 5)
// ---------------------------------------------------------------------------
__global__ __launch_bounds__(256) void k_proj(
    const float* __restrict__ x, const float* __restrict__ W11,
    const float* __restrict__ W12, float4* __restrict__ arr)
{
    __shared__ __align__(16) float w11s[512];   // 16 x 32
    __shared__ __align__(16) float w12d[768];   // 24 x 32, D folded in
    int tid = threadIdx.x;
    for (int i = tid; i < 512; i += 256) w11s[i] = W11[i];
    for (int i = tid; i < 768; i += 256) {
        int r = i >> 5, fc = i & 31;
        int p = r / 3, j = r - p * 3;
        const float* wb = W12 + p * 96 + fc;  // row 3p, col fc
        float v;
        if (j == 0)      v = C00 * wb[0]  + C01 * wb[32];
        else if (j == 1) v = C01 * wb[0]  + C00 * wb[32];
        else             v = C22 * wb[64];
        w12d[i] = v;
    }
    __syncthreads();

    int gid = blockIdx.x * 256 + tid;
    int b = gid & (BT - 1), t = gid >> 9;

    const float4* xv = (const float4*)(x + ((size_t)b * TT + t) * 32);
    float4 xr[8];
    #pragma unroll
    for (int i = 0; i < 8; ++i) xr[i] = xv[i];

    float4* op = arr + ((size_t)(b >> 3) * TT + t) * 64 + (b & 7) * 8;
    #pragma unroll
    for (int p = 0; p < 8; ++p) {
        float dn = 0.f, ds = 0.f, e0 = 0.f, e1 = 0.f, e2 = 0.f;
        const float4* wa = (const float4*)(w11s + p * 64);
        const float4* wb = (const float4*)(w12d + p * 96);
        #pragma unroll
        for (int f = 0; f < 8; ++f) {
            float4 xf = xr[f];
            float4 a0 = wa[f], a1 = wa[8 + f];
            float4 b0 = wb[f], b1 = wb[8 + f], b2 = wb[16 + f];
            dn = fmaf(xf.x, a0.x, dn); dn = fmaf(xf.y, a0.y, dn);
            dn = fmaf(xf.z, a0.z, dn); dn = fmaf(xf.w, a0.w, dn);
            ds = fmaf(xf.x, a1.x, ds); ds = fmaf(xf.y, a1.y, ds);
            ds = fmaf(xf.z, a1.z, ds); ds = fmaf(xf.w, a1.w, ds);
            e0 = fmaf(xf.x, b0.x, e0); e0 = fmaf(xf.y, b0.y, e0);
            e0 = fmaf(xf.z, b0.z, e0); e0 = fmaf(xf.w, b0.w, e0);
            e1 = fmaf(xf.x, b1.x, e1); e1 = fmaf(xf.y, b1.y, e1);
            e1 = fmaf(xf.z, b1.z, e1); e1 = fmaf(xf.w, b1.w, e1);
            e2 = fmaf(xf.x, b2.x, e2); e2 = fmaf(xf.y, b2.y, e2);
            e2 = fmaf(xf.z, b2.z, e2); e2 = fmaf(xf.w, b2.w, e2);
        }
        float dnp = fmaxf(dn, 0.f);
        float lam = sqrtf(fmaf(dnp, dnp, fmaf(ds, ds, 1e-12f)));
        float dnew = (0.1f * (lam - 0.01f)) / (lam * 0.09f);
        dnew = fminf(fmaxf(dnew, 0.f), 1.f);
        op[p] = make_float4(dnew, e0, e1, e2);
    }
}

// ---------------------------------------------------------------------------
// K2: sequential scan, TWO chains per lane (32 blocks x 64 lanes).
// Lane owns chains blk*128+lane and blk*128+64+lane; their independent
// dependence chains interleave to fill VALU latency bubbles.
// LDS-DMA ring: 4 slots x 8 steps x 2 halves (64 KiB), loads issued
// 3 groups (24 steps) ahead; waits counted, capped at vmcnt(63).
// Output chain-major sig[chain][t][3]; 4 steps combined -> 3x dwordx4.
// ---------------------------------------------------------------------------
#define GLOAD(gp, lp) \
    __builtin_amdgcn_global_load_lds( \
        (const __attribute__((address_space(1))) void*)(gp), \
        (__attribute__((address_space(3))) void*)(lp), 16, 0, 0)

struct St { float d, Pxx, Pyy, Pxy, kap; };

__device__ __forceinline__ void scan_step(float4 v, St& s, float* o)
{
    bool loading = v.x > s.d;            // d_new > d_hist
    s.d = fmaxf(s.d, v.x);
    float sxx = v.y - s.Pxx, syy = v.z - s.Pyy, sxy = v.w - s.Pxy;
    float q = fmaf(syy, syy, 1e-12f);
    q = fmaf(sxx, sxx - syy, q);
    q = fmaf(3.0f * sxy, sxy, q);
    float rq  = __builtin_amdgcn_rsqf(q);
    float seq = q * rq;                  // sqrt(q) without the extra trans op
    float sigY = fmaf(100.f, s.kap, 10.f);
    float dk = fmaxf(seq - sigY, 0.f) * INV3GH;
    s.kap += dk;
    float f = fminf(fmaf(100.f, dk, sigY) * rq, 1.f);
    s.Pxx = fmaf(f, s.Pxx - v.y, v.y);
    s.Pyy = fmaf(f, s.Pyy - v.z, v.z);
    s.Pxy = fmaf(f, s.Pxy - v.w, v.w);
    float scale = loading ? f : fmaf(-f, s.d, f);   // f  or  f*(1-d)
    o[0] = scale * sxx; o[1] = scale * syy; o[2] = scale * sxy;
}

template<int WN, bool LD>
__device__ __forceinline__ void do_group2(
    int g, const float4* apA, const float4* apB,
    float4 (&ring)[4][8][2][64], int lane,
    St& A, St& B, float* spA, float* spB)
{
    asm volatile("s_waitcnt vmcnt(%0)" :: "n"(WN) : "memory");
    const int slot = g & 3;
    float4 vA[8], vB[8];
    #pragma unroll
    for (int j = 0; j < 8; ++j) {
        vA[j] = ring[slot][j][0][lane];
        vB[j] = ring[slot][j][1][lane];
    }
    if (LD) {
        const int gl = g + 3, s2 = gl & 3;
        #pragma unroll
        for (int j = 0; j < 8; ++j) {
            GLOAD(apA + (size_t)(gl * 8 + j) * 64, &ring[s2][j][0][0]);
            GLOAD(apB + (size_t)(gl * 8 + j) * 64, &ring[s2][j][1][0]);
        }
    }
    __builtin_amdgcn_sched_barrier(0);   // keep [loads][stores] event order
    float oA[12], oB[12];
    #pragma unroll
    for (int j = 0; j < 8; ++j) {
        scan_step(vA[j], A, &oA[(j & 3) * 3]);
        scan_step(vB[j], B, &oB[(j & 3) * 3]);
        if ((j & 3) == 3) {
            float4* dA = (float4*)(spA + (size_t)(g * 8 + j - 3) * 3);
            dA[0] = make_float4(oA[0], oA[1], oA[2],  oA[3]);
            dA[1] = make_float4(oA[4], oA[5], oA[6],  oA[7]);
            dA[2] = make_float4(oA[8], oA[9], oA[10], oA[11]);
            float4* dB = (float4*)(spB + (size_t)(g * 8 + j - 3) * 3);
            dB[0] = make_float4(oB[0], oB[1], oB[2],  oB[3]);
            dB[1] = make_float4(oB[4], oB[5], oB[6],  oB[7]);
            dB[2] = make_float4(oB[8], oB[9], oB[10], oB[11]);
        }
    }
}

__global__ __launch_bounds__(64) void k_scan(
    const float4* __restrict__ arr, float* __restrict__ sig)
{
    __shared__ float4 ring[4][8][2][64];    // 64 KiB
    const int lane = threadIdx.x, blk = blockIdx.x;
    const float4* apA = arr + (size_t)(2 * blk)     * (TT * 64) + lane;
    const float4* apB = arr + (size_t)(2 * blk + 1) * (TT * 64) + lane;
    const int chainA = blk * 128 + lane, chainB = chainA + 64;
    float* spA = sig + (size_t)chainA * (TT * 3);
    float* spB = sig + (size_t)chainB * (TT * 3);

    St A = {0.f, 0.f, 0.f, 0.f, 0.f};
    St B = {0.f, 0.f, 0.f, 0.f, 0.f};

    // prologue: DMA groups 0..2 into slots 0..2 (48 load events)
    #pragma unroll
    for (int g = 0; g < 3; ++g)
        #pragma unroll
        for (int j = 0; j < 8; ++j) {
            GLOAD(apA + (size_t)(g * 8 + j) * 64, &ring[g][j][0][0]);
            GLOAD(apB + (size_t)(g * 8 + j) * 64, &ring[g][j][1][0]);
        }

    // per-group vmem events: 16 loads + 12 stores; loads for g issued at g-3.
    // exact newer-than-L(g) counts: g0:32 g1:44 g2:56 steady:68 -> capped 63.
    do_group2<32, true >(0, apA, apB, ring, lane, A, B, spA, spB);
    do_group2<44, true >(1, apA, apB, ring, lane, A, B, spA, spB);
    do_group2<56, true >(2, apA, apB, ring, lane, A, B, spA, spB);
    for (int g = 3; g <= 252; ++g)
        do_group2<63, true >(g, apA, apB, ring, lane, A, B, spA, spB);
    do_group2<63, false>(253, apA, apB, ring, lane, A, B, spA, spB);
    do_group2<52, false>(254, apA, apB, ring, lane, A, B, spA, spB);
    do_group2<36, false>(255, apA, apB, ring, lane, A, B, spA, spB);
}

// ---------------------------------------------------------------------------
// K3: out[b][t][:] = sig_row(24) @ softplus(W2)^T. One thread per (b,t).
// sig is chain-major [chain][t][3]; lanes = consecutive t -> each p-stream
// is contiguous 12B/lane (coalesced).
// ---------------------------------------------------------------------------
__global__ __launch_bounds__(256) void k_out(
    const float* __restrict__ sig, const float* __restrict__ W2,
    float* __restrict__ out)
{
    __shared__ __align__(16) float4 w2v[48];   // [k][p] -> (w[k][3p..3p+2],0)
    int tid = threadIdx.x;
    if (tid < 48) {
        int k = tid >> 3, p = tid & 7;
        const float* wr = W2 + k * 24 + 3 * p;
        w2v[tid] = make_float4(softplus_f(wr[0]), softplus_f(wr[1]),
                               softplus_f(wr[2]), 0.f);
    }
    __syncthreads();

    int gid = blockIdx.x * 256 + tid;          // = b*2048 + t
    int b = gid >> 11, t = gid & (TT - 1);

    float sx[8], sy[8], sz[8];
    #pragma unroll
    for (int p = 0; p < 8; ++p) {
        const float* cp = sig + (size_t)(b * 8 + p) * (TT * 3) + t * 3;
        sx[p] = cp[0]; sy[p] = cp[1]; sz[p] = cp[2];
    }
    float o[6];
    #pragma unroll
    for (int k = 0; k < 6; ++k) {
        float acc = 0.f;
        #pragma unroll
        for (int p = 0; p < 8; ++p) {
            float4 w = w2v[k * 8 + p];
            acc = fmaf(sx[p], w.x, acc);
            acc = fmaf(sy[p], w.y, acc);
            acc = fmaf(sz[p], w.z, acc);
        }
        o[k] = acc;
    }
    float2* ov = (float2*)(out + (size_t)gid * 6);
    ov[0] = make_float2(o[0], o[1]);
    ov[1] = make_float2(o[2], o[3]);
    ov[2] = make_float2(o[4], o[5]);
}

extern "C" void kernel_launch(void* const* d_in, const int* in_sizes, int n_in,
                              void* d_out, int out_size, void* d_ws, size_t ws_size,
                              hipStream_t stream)
{
    const float* x   = (const float*)d_in[0];
    const float* W11 = (const float*)d_in[1];
    const float* W12 = (const float*)d_in[2];
    const float* W2  = (const float*)d_in[3];
    float* out = (float*)d_out;

    float4* arr = (float4*)d_ws;                                    // 128 MiB
    float*  sig = (float*)((char*)d_ws + (size_t)TT * NCH * 16);    //  96 MiB

    hipLaunchKernelGGL(k_proj, dim3((BT * TT) / 256), dim3(256), 0, stream,
                       x, W11, W12, arr);
    hipLaunchKernelGGL(k_scan, dim3(NCH / 128), dim3(64), 0, stream, arr, sig);
    hipLaunchKernelGGL(k_out,  dim3((BT * TT) / 256), dim3(256), 0, stream,
                       sig, W2, out);
}

// Round 7
// 357.871 us; speedup vs baseline: 1.4150x; 1.4150x over previous
//
#include <hip/hip_runtime.h>
#include <math.h>

static constexpr int BT  = 512;    // batch
static constexpr int TT  = 2048;   // time steps
static constexpr int NCH = BT * 8; // 4096 chains

// f64-derived constants, cast to f32 exactly as the reference does
static constexpr float C00 = (float)(1000.0 / (1.0 - 0.09));            // D[0][0]
static constexpr float C01 = (float)((1000.0 / (1.0 - 0.09)) * 0.3);    // D[0][1]
static constexpr float C22 = (float)((1000.0 / (1.0 - 0.09)) * 0.35);   // D[2][2]
static constexpr float INV3GH = (float)(1.0 / (3.0 * (1000.0 / 2.6) + 100.0));

__device__ __forceinline__ float softplus_f(float v) {
    return fmaxf(v, 0.0f) + log1pf(expf(-fabsf(v)));
}

struct F3 { float x, y, z; };

// ---------------------------------------------------------------------------
// K1: projections + damage candidate. One thread per (b,t).
// arr[g][t][lane] float4 = (d_new, De_xx, De_yy, De_xy);
// g = b>>3, lane = (b&7)*8 + p.   (identical to round 5)
// ---------------------------------------------------------------------------
__global__ __launch_bounds__(256) void k_proj(
    const float* __restrict__ x, const float* __restrict__ W11,
    const float* __restrict__ W12, float4* __restrict__ arr)
{
    __shared__ __align__(16) float w11s[512];   // 16 x 32
    __shared__ __align__(16) float w12d[768];   // 24 x 32, D folded in
    int tid = threadIdx.x;
    for (int i = tid; i < 512; i += 256) w11s[i] = W11[i];
    for (int i = tid; i < 768; i += 256) {
        int r = i >> 5, fc = i & 31;
        int p = r / 3, j = r - p * 3;
        const float* wb = W12 + p * 96 + fc;  // row 3p, col fc
        float v;
        if (j == 0)      v = C00 * wb[0]  + C01 * wb[32];
        else if (j == 1) v = C01 * wb[0]  + C00 * wb[32];
        else             v = C22 * wb[64];
        w12d[i] = v;
    }
    __syncthreads();

    int gid = blockIdx.x * 256 + tid;
    int b = gid & (BT - 1), t = gid >> 9;

    const float4* xv = (const float4*)(x + ((size_t)b * TT + t) * 32);
    float4 xr[8];
    #pragma unroll
    for (int i = 0; i < 8; ++i) xr[i] = xv[i];

    float4* op = arr + ((size_t)(b >> 3) * TT + t) * 64 + (b & 7) * 8;
    #pragma unroll
    for (int p = 0; p < 8; ++p) {
        float dn = 0.f, ds = 0.f, e0 = 0.f, e1 = 0.f, e2 = 0.f;
        const float4* wa = (const float4*)(w11s + p * 64);
        const float4* wb = (const float4*)(w12d + p * 96);
        #pragma unroll
        for (int f = 0; f < 8; ++f) {
            float4 xf = xr[f];
            float4 a0 = wa[f], a1 = wa[8 + f];
            float4 b0 = wb[f], b1 = wb[8 + f], b2 = wb[16 + f];
            dn = fmaf(xf.x, a0.x, dn); dn = fmaf(xf.y, a0.y, dn);
            dn = fmaf(xf.z, a0.z, dn); dn = fmaf(xf.w, a0.w, dn);
            ds = fmaf(xf.x, a1.x, ds); ds = fmaf(xf.y, a1.y, ds);
            ds = fmaf(xf.z, a1.z, ds); ds = fmaf(xf.w, a1.w, ds);
            e0 = fmaf(xf.x, b0.x, e0); e0 = fmaf(xf.y, b0.y, e0);
            e0 = fmaf(xf.z, b0.z, e0); e0 = fmaf(xf.w, b0.w, e0);
            e1 = fmaf(xf.x, b1.x, e1); e1 = fmaf(xf.y, b1.y, e1);
            e1 = fmaf(xf.z, b1.z, e1); e1 = fmaf(xf.w, b1.w, e1);
            e2 = fmaf(xf.x, b2.x, e2); e2 = fmaf(xf.y, b2.y, e2);
            e2 = fmaf(xf.z, b2.z, e2); e2 = fmaf(xf.w, b2.w, e2);
        }
        float dnp = fmaxf(dn, 0.f);
        float lam = sqrtf(fmaf(dnp, dnp, fmaf(ds, ds, 1e-12f)));
        float dnew = (0.1f * (lam - 0.01f)) / (lam * 0.09f);
        dnew = fminf(fmaxf(dnew, 0.f), 1.f);
        op[p] = make_float4(dnew, e0, e1, e2);
    }
}

// ---------------------------------------------------------------------------
// K2: sequential scan with LDS-DMA staging (round-5 structure) + wave-uniform
// elastic fast path. sigY = 10 + 100*kappa tracked directly (monotone);
// plastic section (rsq, dk, f, P-update) skipped when the whole wave is
// elastic (q <= sigY^2) -- expected ~ln(T) plastic steps per chain.
// Output: damaged stress, packed 12 B at sig[b][t][3p..3p+2].
// ---------------------------------------------------------------------------
#define GLOAD(gp, lp) \
    __builtin_amdgcn_global_load_lds( \
        (const __attribute__((address_space(1))) void*)(gp), \
        (__attribute__((address_space(3))) void*)(lp), 16, 0, 0)

struct St { float d, Pxx, Pyy, Pxy, sigY, sigY2; };

__device__ __forceinline__ void scan_step(float4 v, St& s, float* o)
{
    bool loading = v.x > s.d;            // d_new > d_hist
    s.d = fmaxf(s.d, v.x);
    float sxx = v.y - s.Pxx, syy = v.z - s.Pyy, sxy = v.w - s.Pxy;
    float q = fmaf(syy, syy, 1e-12f);
    q = fmaf(sxx, sxx - syy, q);
    q = fmaf(3.0f * sxy, sxy, q);
    float f = 1.0f;
    if (__any(q > s.sigY2)) {            // wave-uniform plastic section
        float rq  = __builtin_amdgcn_rsqf(q);
        float seq = q * rq;              // sqrt(q)
        float dk  = fmaxf(seq - s.sigY, 0.f) * INV3GH;
        float fn  = fmaf(100.f, dk, s.sigY);   // = new sigY (dk=0 -> old)
        f = fminf(fn * rq, 1.f);
        s.Pxx = fmaf(f, s.Pxx - v.y, v.y);
        s.Pyy = fmaf(f, s.Pyy - v.z, v.z);
        s.Pxy = fmaf(f, s.Pxy - v.w, v.w);
        s.sigY  = fn;
        s.sigY2 = fn * fn;
    }
    float scale = loading ? f : f * (1.0f - s.d);
    o[0] = scale * sxx; o[1] = scale * syy; o[2] = scale * sxy;
}

template<int WN, bool LD>
__device__ __forceinline__ void do_group(
    int g, const float4* ap, float4 (&ring)[4][8][64], int lane,
    St& s, float* sp)
{
    asm volatile("s_waitcnt vmcnt(%0)" :: "n"(WN) : "memory");
    const int slot = g & 3;
    float4 v[8];
    #pragma unroll
    for (int j = 0; j < 8; ++j) v[j] = ring[slot][j][lane];
    if (LD) {
        const int gl = g + 3;
        #pragma unroll
        for (int j = 0; j < 8; ++j)
            GLOAD(ap + (size_t)(gl * 8 + j) * 64, &ring[gl & 3][j][0]);
    }
    __builtin_amdgcn_sched_barrier(0);   // pin [L-pack][S-pack] issue order
    #pragma unroll
    for (int j = 0; j < 8; ++j) {
        float o[3];
        scan_step(v[j], s, o);
        *(F3*)(sp + (size_t)(g * 8 + j) * 24) = {o[0], o[1], o[2]};
    }
}

__global__ __launch_bounds__(64) void k_scan(
    const float4* __restrict__ arr, float* __restrict__ sig)
{
    __shared__ float4 ring[4][8][64];    // 32 KiB
    const int lane = threadIdx.x;
    const float4* ap = arr + (size_t)blockIdx.x * (TT * 64) + lane;
    const int b = blockIdx.x * 8 + (lane >> 3), p = lane & 7;
    float* sp = sig + (size_t)b * (TT * 24) + 3 * p;

    St s = {0.f, 0.f, 0.f, 0.f, 10.f, 100.f};

    // prologue: DMA groups 0..2 (24 loads, no stores yet)
    #pragma unroll
    for (int g = 0; g < 3; ++g)
        #pragma unroll
        for (int j = 0; j < 8; ++j)
            GLOAD(ap + (size_t)(g * 8 + j) * 64, &ring[g][j][0]);

    // exact vmcnt counts (issue order per group pinned to [8 loads][8 stores]):
    // after L(g)'s pack: g=0:16  g=1:24  g=2:32  steady:40  tail: 40/32/24
    do_group<16, true >(0, ap, ring, lane, s, sp);
    do_group<24, true >(1, ap, ring, lane, s, sp);
    do_group<32, true >(2, ap, ring, lane, s, sp);
    for (int g = 3; g <= 252; ++g)
        do_group<40, true >(g, ap, ring, lane, s, sp);
    do_group<40, false>(253, ap, ring, lane, s, sp);
    do_group<32, false>(254, ap, ring, lane, s, sp);
    do_group<24, false>(255, ap, ring, lane, s, sp);
}

// ---------------------------------------------------------------------------
// K3: out[b][t][:] = sig_row(24) @ softplus(W2)^T. One thread per (b,t);
// sig rows are 96 B contiguous -> 6 float4 loads.   (identical to round 5)
// ---------------------------------------------------------------------------
__global__ __launch_bounds__(256) void k_out(
    const float* __restrict__ sig, const float* __restrict__ W2,
    float* __restrict__ out)
{
    __shared__ float w2s[144];
    int tid = threadIdx.x;
    if (tid < 144) w2s[tid] = softplus_f(W2[tid]);
    __syncthreads();

    int gid = blockIdx.x * 256 + tid;          // = b*2048 + t = sig row
    const float4* sp = (const float4*)(sig + (size_t)gid * 24);
    float4 v[6];
    #pragma unroll
    for (int i = 0; i < 6; ++i) v[i] = sp[i];
    float s[24];
    #pragma unroll
    for (int i = 0; i < 6; ++i) {
        s[4*i] = v[i].x; s[4*i+1] = v[i].y; s[4*i+2] = v[i].z; s[4*i+3] = v[i].w;
    }
    float o[6];
    #pragma unroll
    for (int k = 0; k < 6; ++k) {
        float acc = 0.f;
        #pragma unroll
        for (int j = 0; j < 24; ++j) acc = fmaf(s[j], w2s[k * 24 + j], acc);
        o[k] = acc;
    }
    float2* ov = (float2*)(out + (size_t)gid * 6);
    ov[0] = make_float2(o[0], o[1]);
    ov[1] = make_float2(o[2], o[3]);
    ov[2] = make_float2(o[4], o[5]);
}

extern "C" void kernel_launch(void* const* d_in, const int* in_sizes, int n_in,
                              void* d_out, int out_size, void* d_ws, size_t ws_size,
                              hipStream_t stream)
{
    const float* x   = (const float*)d_in[0];
    const float* W11 = (const float*)d_in[1];
    const float* W12 = (const float*)d_in[2];
    const float* W2  = (const float*)d_in[3];
    float* out = (float*)d_out;

    float4* arr = (float4*)d_ws;                                    // 128 MiB
    float*  sig = (float*)((char*)d_ws + (size_t)TT * NCH * 16);    //  96 MiB

    hipLaunchKernelGGL(k_proj, dim3((BT * TT) / 256), dim3(256), 0, stream,
                       x, W11, W12, arr);
    hipLaunchKernelGGL(k_scan, dim3(NCH / 64), dim3(64), 0, stream, arr, sig);
    hipLaunchKernelGGL(k_out,  dim3((BT * TT) / 256), dim3(256), 0, stream,
                       sig, W2, out);
}